// Round 16
// baseline (191.273 us; speedup 1.0000x reference)
//
#include <hip/hip_runtime.h>

namespace {

constexpr int kB = 32;
constexpr int kS = 2048;
constexpr int kD = 64;
constexpr int BQ = 256;       // block rows: 2 chunks x 128 (8 waves x 16 each)
constexpr int CH = 128;       // chunk size
constexpr int BK = 64;        // k rows per tile
constexpr int LW = 72;        // padded LDS row width (f16); 144B rows
constexpr int NT = kS / BK;   // 32 k-tiles
constexpr int NP = NT / 2;    // pass-1 tile pairs
constexpr int KSZ = BK * LW;  // one K/V buffer (elems)
constexpr float kLog2e = 1.44269504088896340736f;

typedef _Float16 f16x8 __attribute__((ext_vector_type(8)));
typedef _Float16 f16x4 __attribute__((ext_vector_type(4)));
typedef float f32x4 __attribute__((ext_vector_type(4)));

#define MFMA16F(a, b, c) __builtin_amdgcn_mfma_f32_16x16x32_f16(a, b, c, 0, 0, 0)

// Barrier draining ONLY the LDS pipe — global loads/stores stay in flight.
#define LBAR()                                                  \
    do {                                                        \
        asm volatile("s_waitcnt lgkmcnt(0)" ::: "memory");      \
        __builtin_amdgcn_s_barrier();                           \
        asm volatile("" ::: "memory");                          \
    } while (0)

__global__ __launch_bounds__(512, 2)
void sdpa_kernel(const float* __restrict__ qg, const float* __restrict__ kg,
                 const float* __restrict__ vg, float* __restrict__ out) {
    // 4 K/V buffers + 8-wave P = 27648 f16 = 55296 B; grid 256 -> 1 block/CU
    __shared__ _Float16 smem[4 * KSZ + 8 * 16 * LW];
    _Float16* sP = smem + 4 * KSZ;       // 8 waves x [16][72]
    _Float16* sQ = smem;                 // Q staging [256][72] overlays all 4 bufs

    const int tid = threadIdx.x;
    const int lane = tid & 63;
    const int g = lane >> 4;          // 0..3
    const int c = lane & 15;          // 0..15
    const int wq = tid >> 6;          // wave 0..7
    const int wrow0 = wq * 16;

    // XCD-chunked swizzle (bijective: 256 = 8 XCD * 32): XCD x gets 4
    // consecutive batches x all 8 q-blocks -> K/V (~8MB) mostly L2-resident.
    const int id = blockIdx.x;
    const int lin = (id & 7) * 32 + (id >> 3);
    const int b = lin >> 3;
    const int q0 = (lin & 7) * BQ;

    float* ctx = out;                                  // [B,S,D]
    float* att = out + (size_t)kB * kS * kD;           // [B,S,S]
    const size_t inb = (size_t)b * kS * kD;
    const float* kbase = kg + inb;

    const int srow = tid >> 4;          // staging row base 0..31
    const int scol = (tid & 15) * 4;    // staging col (elems)

    // V^T staging map: wave wq stages j-slice [8*wq, 8*wq+8) for all 64 d
    const int vd = lane;                // d index 0..63
    const int j0v = wq * 8;

    // att store map (r14): lane -> (row group ar, col4) so one store covers
    // 4 FULL 256B rows per instruction.
    const int ar = lane >> 4;           // 0..3
    const int ac4 = (lane & 15) * 4;    // 0..60

    // ---------- issue K tiles 0,1 prefetch first (deepest latency cover) ----------
    f32x4 kr[2][2];
    #pragma unroll
    for (int t = 0; t < 2; ++t)
        #pragma unroll
        for (int i = 0; i < 2; ++i)
            kr[t][i] = *reinterpret_cast<const f32x4*>(
                kbase + (size_t)(t * BK + i * 32 + srow) * kD + scol);

    // ---------- stage Q for BOTH chunks (f16, pre-scaled by log2e) ----------
    #pragma unroll
    for (int i = 0; i < 8; ++i) {
        const int row = i * 32 + srow;
        f32x4 qv = *reinterpret_cast<const f32x4*>(qg + inb + (size_t)(q0 + row) * kD + scol);
        f16x4 hv;
        #pragma unroll
        for (int e = 0; e < 4; ++e) hv[e] = (_Float16)(qv[e] * kLog2e);
        *reinterpret_cast<f16x4*>(&sQ[row * LW + scol]) = hv;
    }
    LBAR();
    // hoisted Q B-fragments: n = c (q-row wrow0+c within chunk)
    f16x8 aQ0 = *reinterpret_cast<const f16x8*>(&sQ[(wrow0 + c) * LW + 8 * g]);
    f16x8 aQ1 = *reinterpret_cast<const f16x8*>(&sQ[(wrow0 + c) * LW + 32 + 8 * g]);
    f16x8 aQ2 = *reinterpret_cast<const f16x8*>(&sQ[(CH + wrow0 + c) * LW + 8 * g]);
    f16x8 aQ3 = *reinterpret_cast<const f16x8*>(&sQ[(CH + wrow0 + c) * LW + 32 + 8 * g]);
    LBAR();   // Q-fragment reads done before K staging overwrites

    // ================= S1: pass 1 for C0 (2 tiles per barrier, 4-buffer ring) ====
    #pragma unroll
    for (int t = 0; t < 2; ++t)
        #pragma unroll
        for (int i = 0; i < 2; ++i) {
            const int row = i * 32 + srow;
            f16x4 hv;
            #pragma unroll
            for (int e = 0; e < 4; ++e) hv[e] = (_Float16)kr[t][i][e];
            *reinterpret_cast<f16x4*>(&smem[t * KSZ + row * LW + scol]) = hv;
        }
    #pragma unroll
    for (int t = 0; t < 2; ++t)
        #pragma unroll
        for (int i = 0; i < 2; ++i)
            kr[t][i] = *reinterpret_cast<const f32x4*>(
                kbase + (size_t)((2 + t) * BK + i * 32 + srow) * kD + scol);
    LBAR();

    f32x4 l4 = {0.f, 0.f, 0.f, 0.f};

    for (int pt = 0; pt < NP; ++pt) {
        const _Float16* bcur = smem + (pt & 1) * 2 * KSZ;
        _Float16* bnxt = smem + ((pt + 1) & 1) * 2 * KSZ;
        if (pt + 1 < NP) {
            #pragma unroll
            for (int t = 0; t < 2; ++t)
                #pragma unroll
                for (int i = 0; i < 2; ++i) {
                    const int row = i * 32 + srow;
                    f16x4 hv;
                    #pragma unroll
                    for (int e = 0; e < 4; ++e) hv[e] = (_Float16)kr[t][i][e];
                    *reinterpret_cast<f16x4*>(&bnxt[t * KSZ + row * LW + scol]) = hv;
                }
        }
        if (pt + 2 < NP) {
            #pragma unroll
            for (int t = 0; t < 2; ++t)
                #pragma unroll
                for (int i = 0; i < 2; ++i)
                    kr[t][i] = *reinterpret_cast<const f32x4*>(
                        kbase + (size_t)(((pt + 2) * 2 + t) * BK + i * 32 + srow) * kD + scol);
        }
        __builtin_amdgcn_s_setprio(1);
        #pragma unroll
        for (int t = 0; t < 2; ++t) {
            const _Float16* sKc = bcur + t * KSZ;
            #pragma unroll
            for (int ct = 0; ct < 4; ++ct) {
                const int jc = 16 * ct + c;
                f16x8 b0 = *reinterpret_cast<const f16x8*>(&sKc[jc * LW + 8 * g]);
                f16x8 b1 = *reinterpret_cast<const f16x8*>(&sKc[jc * LW + 32 + 8 * g]);
                f32x4 s = {0.f, 0.f, 0.f, 0.f};
                s = MFMA16F(b0, aQ0, s);
                s = MFMA16F(b1, aQ1, s);
                #pragma unroll
                for (int r = 0; r < 4; ++r)
                    l4[r] += __builtin_amdgcn_exp2f(s[r]);
            }
        }
        __builtin_amdgcn_s_setprio(0);
        if (pt + 1 < NP) LBAR();
    }
    float l0 = (l4[0] + l4[1]) + (l4[2] + l4[3]);

    // S2 tile-0/1 prefetch (before the merge to overlap)
    f32x4 kr2[2];
    float vr[8];
    #pragma unroll
    for (int i = 0; i < 2; ++i)
        kr2[i] = *reinterpret_cast<const f32x4*>(kbase + (size_t)(i * 32 + srow) * kD + scol);
    #pragma unroll
    for (int e = 0; e < 8; ++e)
        vr[e] = vg[inb + (size_t)(j0v + e) * kD + vd];

    l0 += __shfl_xor(l0, 16);
    l0 += __shfl_xor(l0, 32);
    const float dexp0 = -__builtin_amdgcn_logf(l0);

    // ================= S2: pass 2 (C0) + pass 1 (C1) on shared K tiles =========
    f32x4 accpv[4];
    #pragma unroll
    for (int dt = 0; dt < 4; ++dt) accpv[dt] = {0.f, 0.f, 0.f, 0.f};
    f32x4 l14 = {0.f, 0.f, 0.f, 0.f};

    _Float16* myP = sP + wq * 16 * LW;

    LBAR();   // S1 final-pair LDS reads drained before restage
    #pragma unroll
    for (int i = 0; i < 2; ++i) {
        const int row = i * 32 + srow;
        f16x4 hv;
        #pragma unroll
        for (int e = 0; e < 4; ++e) hv[e] = (_Float16)kr2[i][e];
        *reinterpret_cast<f16x4*>(&smem[row * LW + scol]) = hv;
    }
    {
        f16x8 vv;
        #pragma unroll
        for (int e = 0; e < 8; ++e) vv[e] = (_Float16)vr[e];
        *reinterpret_cast<f16x8*>(&smem[2 * KSZ + vd * LW + j0v]) = vv;
    }
    #pragma unroll
    for (int i = 0; i < 2; ++i)
        kr2[i] = *reinterpret_cast<const f32x4*>(kbase + (size_t)(BK + i * 32 + srow) * kD + scol);
    #pragma unroll
    for (int e = 0; e < 8; ++e)
        vr[e] = vg[inb + (size_t)(BK + j0v + e) * kD + vd];
    LBAR();

    for (int kt = 0; kt < NT; ++kt) {
        const int j0 = kt * BK;
        const _Float16* sKc = smem + (kt & 1) * KSZ;
        const _Float16* sVc = smem + 2 * KSZ + (kt & 1) * KSZ;
        _Float16* sKn = smem + ((kt + 1) & 1) * KSZ;
        _Float16* sVn = smem + 2 * KSZ + ((kt + 1) & 1) * KSZ;
        if (kt + 1 < NT) {
            #pragma unroll
            for (int i = 0; i < 2; ++i) {
                const int row = i * 32 + srow;
                f16x4 hv;
                #pragma unroll
                for (int e = 0; e < 4; ++e) hv[e] = (_Float16)kr2[i][e];
                *reinterpret_cast<f16x4*>(&sKn[row * LW + scol]) = hv;
            }
            f16x8 vv;
            #pragma unroll
            for (int e = 0; e < 8; ++e) vv[e] = (_Float16)vr[e];
            *reinterpret_cast<f16x8*>(&sVn[vd * LW + j0v]) = vv;
        }
        if (kt + 2 < NT) {
            const int j0n = (kt + 2) * BK;
            #pragma unroll
            for (int i = 0; i < 2; ++i)
                kr2[i] = *reinterpret_cast<const f32x4*>(kbase + (size_t)(j0n + i * 32 + srow) * kD + scol);
            #pragma unroll
            for (int e = 0; e < 8; ++e)
                vr[e] = vg[inb + (size_t)(j0n + j0v + e) * kD + vd];
        }
        __builtin_amdgcn_s_setprio(1);
        #pragma unroll
        for (int ct = 0; ct < 4; ++ct) {
            const int jc = 16 * ct + c;
            f16x8 b0 = *reinterpret_cast<const f16x8*>(&sKc[jc * LW + 8 * g]);
            f16x8 b1 = *reinterpret_cast<const f16x8*>(&sKc[jc * LW + 32 + 8 * g]);
            // pass 2 for C0 (normalized via accumulator-folded dexp0)
            f32x4 s0 = {dexp0, dexp0, dexp0, dexp0};
            s0 = MFMA16F(b0, aQ0, s0);
            s0 = MFMA16F(b1, aQ1, s0);
            f16x4 pv;
            #pragma unroll
            for (int r = 0; r < 4; ++r)
                pv[r] = (_Float16)__builtin_amdgcn_exp2f(s0[r]);
            *reinterpret_cast<f16x4*>(&myP[c * LW + 16 * ct + 4 * g]) = pv;
            // pass 1 for C1 (same b0/b1 — K fragments shared between chunks)
            f32x4 s1 = {0.f, 0.f, 0.f, 0.f};
            s1 = MFMA16F(b0, aQ2, s1);
            s1 = MFMA16F(b1, aQ3, s1);
            #pragma unroll
            for (int r = 0; r < 4; ++r)
                l14[r] += __builtin_amdgcn_exp2f(s1[r]);
        }
        // PV accumulate for C0
        f16x8 aP0 = *reinterpret_cast<const f16x8*>(&myP[c * LW + 8 * g]);
        f16x8 aP1 = *reinterpret_cast<const f16x8*>(&myP[c * LW + 32 + 8 * g]);
        #pragma unroll
        for (int dt = 0; dt < 4; ++dt) {
            f16x8 bv0 = *reinterpret_cast<const f16x8*>(&sVc[(16 * dt + c) * LW + 8 * g]);
            f16x8 bv1 = *reinterpret_cast<const f16x8*>(&sVc[(16 * dt + c) * LW + 32 + 8 * g]);
            accpv[dt] = MFMA16F(aP0, bv0, accpv[dt]);
            accpv[dt] = MFMA16F(aP1, bv1, accpv[dt]);
        }
        __builtin_amdgcn_s_setprio(0);
        // att(C0) store via sP readback: 4 FULL 256B rows per instruction
        #pragma unroll
        for (int i = 0; i < 4; ++i) {
            const int row = 4 * i + ar;
            f16x4 pr = *reinterpret_cast<const f16x4*>(&myP[row * LW + ac4]);
            f32x4 o = {(float)pr[0], (float)pr[1], (float)pr[2], (float)pr[3]};
            *reinterpret_cast<f32x4*>(
                att + ((size_t)b * kS + (size_t)(q0 + wrow0 + row)) * kS + j0 + ac4) = o;
        }
        if (kt + 1 < NT) LBAR();
    }

    // S3 tile-0/1 prefetch (before merge/epilogue to overlap)
    #pragma unroll
    for (int i = 0; i < 2; ++i)
        kr2[i] = *reinterpret_cast<const f32x4*>(kbase + (size_t)(i * 32 + srow) * kD + scol);
    #pragma unroll
    for (int e = 0; e < 8; ++e)
        vr[e] = vg[inb + (size_t)(j0v + e) * kD + vd];

    float l1 = (l14[0] + l14[1]) + (l14[2] + l14[3]);
    l1 += __shfl_xor(l1, 16);
    l1 += __shfl_xor(l1, 32);
    const float dexp1 = -__builtin_amdgcn_logf(l1);

    // ctx epilogue for C0 (stores fly across the coming LBARs)
    #pragma unroll
    for (int dt = 0; dt < 4; ++dt) {
        #pragma unroll
        for (int r = 0; r < 4; ++r) {
            const size_t rowg = (size_t)b * kS + (size_t)(q0 + wrow0 + 4 * g + r);
            const int d = 16 * dt + c;
            ctx[rowg * kD + d] = accpv[dt][r] + qg[rowg * kD + d];
        }
    }

    // ================= S3: pass 2 for C1 =======================================
    #pragma unroll
    for (int dt = 0; dt < 4; ++dt) accpv[dt] = {0.f, 0.f, 0.f, 0.f};

    LBAR();   // S2 final-tile LDS reads drained before restage
    #pragma unroll
    for (int i = 0; i < 2; ++i) {
        const int row = i * 32 + srow;
        f16x4 hv;
        #pragma unroll
        for (int e = 0; e < 4; ++e) hv[e] = (_Float16)kr2[i][e];
        *reinterpret_cast<f16x4*>(&smem[row * LW + scol]) = hv;
    }
    {
        f16x8 vv;
        #pragma unroll
        for (int e = 0; e < 8; ++e) vv[e] = (_Float16)vr[e];
        *reinterpret_cast<f16x8*>(&smem[2 * KSZ + vd * LW + j0v]) = vv;
    }
    #pragma unroll
    for (int i = 0; i < 2; ++i)
        kr2[i] = *reinterpret_cast<const f32x4*>(kbase + (size_t)(BK + i * 32 + srow) * kD + scol);
    #pragma unroll
    for (int e = 0; e < 8; ++e)
        vr[e] = vg[inb + (size_t)(BK + j0v + e) * kD + vd];
    LBAR();

    for (int kt = 0; kt < NT; ++kt) {
        const int j0 = kt * BK;
        const _Float16* sKc = smem + (kt & 1) * KSZ;
        const _Float16* sVc = smem + 2 * KSZ + (kt & 1) * KSZ;
        _Float16* sKn = smem + ((kt + 1) & 1) * KSZ;
        _Float16* sVn = smem + 2 * KSZ + ((kt + 1) & 1) * KSZ;
        if (kt + 1 < NT) {
            #pragma unroll
            for (int i = 0; i < 2; ++i) {
                const int row = i * 32 + srow;
                f16x4 hv;
                #pragma unroll
                for (int e = 0; e < 4; ++e) hv[e] = (_Float16)kr2[i][e];
                *reinterpret_cast<f16x4*>(&sKn[row * LW + scol]) = hv;
            }
            f16x8 vv;
            #pragma unroll
            for (int e = 0; e < 8; ++e) vv[e] = (_Float16)vr[e];
            *reinterpret_cast<f16x8*>(&sVn[vd * LW + j0v]) = vv;
        }
        if (kt + 2 < NT) {
            const int j0n = (kt + 2) * BK;
            #pragma unroll
            for (int i = 0; i < 2; ++i)
                kr2[i] = *reinterpret_cast<const f32x4*>(kbase + (size_t)(j0n + i * 32 + srow) * kD + scol);
            #pragma unroll
            for (int e = 0; e < 8; ++e)
                vr[e] = vg[inb + (size_t)(j0n + j0v + e) * kD + vd];
        }
        __builtin_amdgcn_s_setprio(1);
        #pragma unroll
        for (int ct = 0; ct < 4; ++ct) {
            const int jc = 16 * ct + c;
            f16x8 b0 = *reinterpret_cast<const f16x8*>(&sKc[jc * LW + 8 * g]);
            f16x8 b1 = *reinterpret_cast<const f16x8*>(&sKc[jc * LW + 32 + 8 * g]);
            f32x4 s = {dexp1, dexp1, dexp1, dexp1};
            s = MFMA16F(b0, aQ2, s);
            s = MFMA16F(b1, aQ3, s);
            f16x4 pv;
            #pragma unroll
            for (int r = 0; r < 4; ++r)
                pv[r] = (_Float16)__builtin_amdgcn_exp2f(s[r]);
            *reinterpret_cast<f16x4*>(&myP[c * LW + 16 * ct + 4 * g]) = pv;
        }
        f16x8 aP0 = *reinterpret_cast<const f16x8*>(&myP[c * LW + 8 * g]);
        f16x8 aP1 = *reinterpret_cast<const f16x8*>(&myP[c * LW + 32 + 8 * g]);
        #pragma unroll
        for (int dt = 0; dt < 4; ++dt) {
            f16x8 bv0 = *reinterpret_cast<const f16x8*>(&sVc[(16 * dt + c) * LW + 8 * g]);
            f16x8 bv1 = *reinterpret_cast<const f16x8*>(&sVc[(16 * dt + c) * LW + 32 + 8 * g]);
            accpv[dt] = MFMA16F(aP0, bv0, accpv[dt]);
            accpv[dt] = MFMA16F(aP1, bv1, accpv[dt]);
        }
        __builtin_amdgcn_s_setprio(0);
        #pragma unroll
        for (int i = 0; i < 4; ++i) {
            const int row = 4 * i + ar;
            f16x4 pr = *reinterpret_cast<const f16x4*>(&myP[row * LW + ac4]);
            f32x4 o = {(float)pr[0], (float)pr[1], (float)pr[2], (float)pr[3]};
            *reinterpret_cast<f32x4*>(
                att + ((size_t)b * kS + (size_t)(q0 + CH + wrow0 + row)) * kS + j0 + ac4) = o;
        }
        if (kt + 1 < NT) LBAR();
    }

    // ctx epilogue for C1
    #pragma unroll
    for (int dt = 0; dt < 4; ++dt) {
        #pragma unroll
        for (int r = 0; r < 4; ++r) {
            const size_t rowg = (size_t)b * kS + (size_t)(q0 + CH + wrow0 + 4 * g + r);
            const int d = 16 * dt + c;
            ctx[rowg * kD + d] = accpv[dt][r] + qg[rowg * kD + d];
        }
    }
}

}  // namespace

extern "C" void kernel_launch(void* const* d_in, const int* in_sizes, int n_in,
                              void* d_out, int out_size, void* d_ws, size_t ws_size,
                              hipStream_t stream) {
    const float* q = (const float*)d_in[0];
    const float* k = (const float*)d_in[1];
    const float* v = (const float*)d_in[2];
    float* out = (float*)d_out;
    dim3 grid(kB * (kS / BQ));
    dim3 block(512);
    hipLaunchKernelGGL(sdpa_kernel, grid, block, 0, stream, q, k, v, out);
}

// Round 17
// 159.290 us; speedup vs baseline: 1.2008x; 1.2008x over previous
//
#include <hip/hip_runtime.h>

namespace {

constexpr int kB = 32;
constexpr int kS = 2048;
constexpr int kD = 64;
constexpr int BQ = 128;       // q rows per block (8 waves x 16)
constexpr int BK = 64;        // k rows per tile
constexpr int LW = 72;        // padded LDS row width (f16); 144B rows
constexpr int LWP = 136;      // P batch row width: 128 cols (2 tiles) + 8 pad
constexpr int NT = kS / BK;   // 32 k-tiles
constexpr int NP = NT / 2;    // pass-1 tile pairs
constexpr int KSZ = BK * LW;  // one K/V buffer (elems)
constexpr float kLog2e = 1.44269504088896340736f;

typedef _Float16 f16x8 __attribute__((ext_vector_type(8)));
typedef _Float16 f16x4 __attribute__((ext_vector_type(4)));
typedef float f32x4 __attribute__((ext_vector_type(4)));

#define MFMA16F(a, b, c) __builtin_amdgcn_mfma_f32_16x16x32_f16(a, b, c, 0, 0, 0)

// Barrier draining ONLY the LDS pipe — global loads/stores stay in flight.
#define LBAR()                                                  \
    do {                                                        \
        asm volatile("s_waitcnt lgkmcnt(0)" ::: "memory");      \
        __builtin_amdgcn_s_barrier();                           \
        asm volatile("" ::: "memory");                          \
    } while (0)

__global__ __launch_bounds__(512, 4)
void sdpa_kernel(const float* __restrict__ qg, const float* __restrict__ kg,
                 const float* __restrict__ vg, float* __restrict__ out) {
    // 4 K/V buffers (36864B) + 8-wave P batch (8x16x136x2 = 34816B) = 71680B
    // -> 2 blocks/CU (16 waves)
    __shared__ _Float16 smem[4 * KSZ + 8 * 16 * LWP];
    _Float16* sP = smem + 4 * KSZ;       // 8 waves x [16][136] (2-tile P batch)
    _Float16* sQ = smem;                 // Q staging [128][72] overlays buf0+buf1

    const int tid = threadIdx.x;
    const int lane = tid & 63;
    const int g = lane >> 4;          // 0..3
    const int c = lane & 15;          // 0..15
    const int wq = tid >> 6;          // wave 0..7
    const int wrow0 = wq * 16;

    // XCD-chunked swizzle (bijective: 512 = 8 XCD * 64): XCD x gets 4
    // consecutive batches x all 16 q-blocks -> K/V (~4MB) L2-resident per XCD.
    const int id = blockIdx.x;
    const int lin = (id & 7) * 64 + (id >> 3);
    const int b = lin >> 4;
    const int q0 = (lin & 15) * BQ;

    float* ctx = out;                                  // [B,S,D]
    float* att = out + (size_t)kB * kS * kD;           // [B,S,S]
    const size_t inb = (size_t)b * kS * kD;
    const float* kbase = kg + inb;

    const int srow = tid >> 4;          // staging row base 0..31
    const int scol = (tid & 15) * 4;    // staging col (elems)

    // V^T staging map: wave wq stages j-slice [8*wq, 8*wq+8) for all 64 d
    const int vd = lane;                // d index 0..63
    const int j0v = wq * 8;

    // att dump map (2-tile batch): lane -> (row parity dr, col4) so one store
    // covers 2 FULL 512B row-segments per instruction.
    const int dr = lane >> 5;           // 0..1
    const int dc4 = (lane & 31) * 4;    // 0..124

    // ---------- issue K tiles 0,1 prefetch first (deepest latency cover) ----------
    f32x4 kr[2][2];
    #pragma unroll
    for (int t = 0; t < 2; ++t)
        #pragma unroll
        for (int i = 0; i < 2; ++i)
            kr[t][i] = *reinterpret_cast<const f32x4*>(
                kbase + (size_t)(t * BK + i * 32 + srow) * kD + scol);

    // ---------- stage Q (f16, pre-scaled by log2e -> scores in log2 domain) ----------
    #pragma unroll
    for (int i = 0; i < 4; ++i) {
        const int row = i * 32 + srow;
        f32x4 qv = *reinterpret_cast<const f32x4*>(qg + inb + (size_t)(q0 + row) * kD + scol);
        f16x4 hv;
        #pragma unroll
        for (int e = 0; e < 4; ++e) hv[e] = (_Float16)(qv[e] * kLog2e);
        *reinterpret_cast<f16x4*>(&sQ[row * LW + scol]) = hv;
    }
    LBAR();
    // hoisted Q B-fragments: n = c (q-row wrow0+c), k = kk*32 + 8*g + e
    f16x8 aQ0 = *reinterpret_cast<const f16x8*>(&sQ[(wrow0 + c) * LW + 8 * g]);
    f16x8 aQ1 = *reinterpret_cast<const f16x8*>(&sQ[(wrow0 + c) * LW + 32 + 8 * g]);
    LBAR();   // Q-fragment reads done before K staging overwrites

    // ---------- pass 1: softmax denominator; 2 tiles per barrier (4-buffer ring) ----------
    // prologue: stage tiles 0,1 into buf0,1; prefetch tiles 2,3
    #pragma unroll
    for (int t = 0; t < 2; ++t)
        #pragma unroll
        for (int i = 0; i < 2; ++i) {
            const int row = i * 32 + srow;
            f16x4 hv;
            #pragma unroll
            for (int e = 0; e < 4; ++e) hv[e] = (_Float16)kr[t][i][e];
            *reinterpret_cast<f16x4*>(&smem[t * KSZ + row * LW + scol]) = hv;
        }
    #pragma unroll
    for (int t = 0; t < 2; ++t)
        #pragma unroll
        for (int i = 0; i < 2; ++i)
            kr[t][i] = *reinterpret_cast<const f32x4*>(
                kbase + (size_t)((2 + t) * BK + i * 32 + srow) * kD + scol);
    LBAR();

    // 4-way split accumulator (breaks the serial v_add chain in the inner loop)
    f32x4 l4 = {0.f, 0.f, 0.f, 0.f};

    for (int pt = 0; pt < NP; ++pt) {
        const _Float16* bcur = smem + (pt & 1) * 2 * KSZ;
        _Float16* bnxt = smem + ((pt + 1) & 1) * 2 * KSZ;
        if (pt + 1 < NP) {               // stage next pair from prefetch regs
            #pragma unroll
            for (int t = 0; t < 2; ++t)
                #pragma unroll
                for (int i = 0; i < 2; ++i) {
                    const int row = i * 32 + srow;
                    f16x4 hv;
                    #pragma unroll
                    for (int e = 0; e < 4; ++e) hv[e] = (_Float16)kr[t][i][e];
                    *reinterpret_cast<f16x4*>(&bnxt[t * KSZ + row * LW + scol]) = hv;
                }
        }
        if (pt + 2 < NP) {               // issue pair+2 loads
            #pragma unroll
            for (int t = 0; t < 2; ++t)
                #pragma unroll
                for (int i = 0; i < 2; ++i)
                    kr[t][i] = *reinterpret_cast<const f32x4*>(
                        kbase + (size_t)(((pt + 2) * 2 + t) * BK + i * 32 + srow) * kD + scol);
        }
        __builtin_amdgcn_s_setprio(1);
        #pragma unroll
        for (int t = 0; t < 2; ++t) {
            const _Float16* sKc = bcur + t * KSZ;
            #pragma unroll
            for (int ct = 0; ct < 4; ++ct) {
                const int jc = 16 * ct + c;
                f16x8 b0 = *reinterpret_cast<const f16x8*>(&sKc[jc * LW + 8 * g]);
                f16x8 b1 = *reinterpret_cast<const f16x8*>(&sKc[jc * LW + 32 + 8 * g]);
                f32x4 s = {0.f, 0.f, 0.f, 0.f};
                s = MFMA16F(b0, aQ0, s);  // lane holds S2[q=wrow0+c][j=...] (log2 dom.)
                s = MFMA16F(b1, aQ1, s);
                #pragma unroll
                for (int r = 0; r < 4; ++r)
                    l4[r] += __builtin_amdgcn_exp2f(s[r]);   // raw 2^s2, no shift
            }
        }
        __builtin_amdgcn_s_setprio(0);
        if (pt + 1 < NP) LBAR();         // one barrier per 2 tiles
    }
    float l_l = (l4[0] + l4[1]) + (l4[2] + l4[3]);

    // pass-2 tile-0/1 prefetch (issue before the shuffle merge to overlap)
    f32x4 kr2[2];
    float vr[8];
    #pragma unroll
    for (int i = 0; i < 2; ++i)
        kr2[i] = *reinterpret_cast<const f32x4*>(kbase + (size_t)(i * 32 + srow) * kD + scol);
    #pragma unroll
    for (int e = 0; e < 8; ++e)
        vr[e] = vg[inb + (size_t)(j0v + e) * kD + vd];

    // merge l across the 4 g-groups holding the same q-row
    l_l += __shfl_xor(l_l, 16);
    l_l += __shfl_xor(l_l, 32);
    // normalization exponent: p = 2^(s2 + d) = exp(s)/l  (v_log_f32 is log2)
    const float dexp = -__builtin_amdgcn_logf(l_l);

    // ---------- pass 2: attention write + PV (f16 scores/P/V) ----------
    f32x4 accpv[4];
    #pragma unroll
    for (int dt = 0; dt < 4; ++dt) accpv[dt] = {0.f, 0.f, 0.f, 0.f};

    _Float16* myP = sP + wq * 16 * LWP;

    LBAR();   // pass-1 final-pair LDS reads drained before restage
    // prologue: stage K/V tile 0 into buf0, prefetch tile 1
    #pragma unroll
    for (int i = 0; i < 2; ++i) {
        const int row = i * 32 + srow;
        f16x4 hv;
        #pragma unroll
        for (int e = 0; e < 4; ++e) hv[e] = (_Float16)kr2[i][e];
        *reinterpret_cast<f16x4*>(&smem[row * LW + scol]) = hv;
    }
    {
        f16x8 vv;
        #pragma unroll
        for (int e = 0; e < 8; ++e) vv[e] = (_Float16)vr[e];
        *reinterpret_cast<f16x8*>(&smem[2 * KSZ + vd * LW + j0v]) = vv;
    }
    #pragma unroll
    for (int i = 0; i < 2; ++i)
        kr2[i] = *reinterpret_cast<const f32x4*>(kbase + (size_t)(BK + i * 32 + srow) * kD + scol);
    #pragma unroll
    for (int e = 0; e < 8; ++e)
        vr[e] = vg[inb + (size_t)(BK + j0v + e) * kD + vd];
    LBAR();

    for (int kt = 0; kt < NT; ++kt) {
        const int jo2 = (kt & 1) * 64;   // column offset within the 2-tile P batch
        const _Float16* sKc = smem + (kt & 1) * KSZ;
        const _Float16* sVc = smem + 2 * KSZ + (kt & 1) * KSZ;
        _Float16* sKn = smem + ((kt + 1) & 1) * KSZ;
        _Float16* sVn = smem + 2 * KSZ + ((kt + 1) & 1) * KSZ;
        if (kt + 1 < NT) {               // stage next K/V from prefetch regs
            #pragma unroll
            for (int i = 0; i < 2; ++i) {
                const int row = i * 32 + srow;
                f16x4 hv;
                #pragma unroll
                for (int e = 0; e < 4; ++e) hv[e] = (_Float16)kr2[i][e];
                *reinterpret_cast<f16x4*>(&sKn[row * LW + scol]) = hv;
            }
            f16x8 vv;
            #pragma unroll
            for (int e = 0; e < 8; ++e) vv[e] = (_Float16)vr[e];
            *reinterpret_cast<f16x8*>(&sVn[vd * LW + j0v]) = vv;
        }
        if (kt + 2 < NT) {               // issue tile t+2 loads
            const int j0n = (kt + 2) * BK;
            #pragma unroll
            for (int i = 0; i < 2; ++i)
                kr2[i] = *reinterpret_cast<const f32x4*>(kbase + (size_t)(j0n + i * 32 + srow) * kD + scol);
            #pragma unroll
            for (int e = 0; e < 8; ++e)
                vr[e] = vg[inb + (size_t)(j0n + j0v + e) * kD + vd];
        }
        __builtin_amdgcn_s_setprio(1);
        #pragma unroll
        for (int ct = 0; ct < 4; ++ct) {
            const int jc = 16 * ct + c;
            f16x8 b0 = *reinterpret_cast<const f16x8*>(&sKc[jc * LW + 8 * g]);
            f16x8 b1 = *reinterpret_cast<const f16x8*>(&sKc[jc * LW + 32 + 8 * g]);
            // accumulator pre-init with d: MFMA computes s2 + d for free
            f32x4 s = {dexp, dexp, dexp, dexp};
            s = MFMA16F(b0, aQ0, s);
            s = MFMA16F(b1, aQ1, s);
            f16x4 pv;
            #pragma unroll
            for (int r = 0; r < 4; ++r)
                pv[r] = (_Float16)__builtin_amdgcn_exp2f(s[r]);  // = exp(s)/l
            // P[q=c][j=jo2+16ct+4g..+3] -> single packed b64
            *reinterpret_cast<f16x4*>(&myP[c * LWP + jo2 + 16 * ct + 4 * g]) = pv;
        }
        // PV accumulate (myP wave-private; in-wave lgkm ordering suffices)
        f16x8 aP0 = *reinterpret_cast<const f16x8*>(&myP[c * LWP + jo2 + 8 * g]);
        f16x8 aP1 = *reinterpret_cast<const f16x8*>(&myP[c * LWP + jo2 + 32 + 8 * g]);
        #pragma unroll
        for (int dt = 0; dt < 4; ++dt) {
            f16x8 bv0 = *reinterpret_cast<const f16x8*>(&sVc[(16 * dt + c) * LW + 8 * g]);
            f16x8 bv1 = *reinterpret_cast<const f16x8*>(&sVc[(16 * dt + c) * LW + 32 + 8 * g]);
            accpv[dt] = MFMA16F(aP0, bv0, accpv[dt]);
            accpv[dt] = MFMA16F(aP1, bv1, accpv[dt]);
        }
        __builtin_amdgcn_s_setprio(0);
        // att dump every 2 tiles: one instruction = 2 FULL 512B row-segments
        // (vs 4 x 256B before — longer HBM write bursts, half the store instrs)
        if (kt & 1) {
            const int jb = (kt - 1) * BK;
            #pragma unroll
            for (int i = 0; i < 8; ++i) {
                const int row = 2 * i + dr;
                f16x4 pr = *reinterpret_cast<const f16x4*>(&myP[row * LWP + dc4]);
                f32x4 o = {(float)pr[0], (float)pr[1], (float)pr[2], (float)pr[3]};
                *reinterpret_cast<f32x4*>(
                    att + ((size_t)b * kS + (size_t)(q0 + wrow0 + row)) * kS + jb + dc4) = o;
            }
        }
        if (kt + 1 < NT) LBAR();         // one barrier per tile
    }

    // ---------- epilogue: context = PV + q ----------
    // accpv: C[m=4g+r][n=c] -> q-row wrow0+4g+r, d = 16dt+c
    #pragma unroll
    for (int dt = 0; dt < 4; ++dt) {
        #pragma unroll
        for (int r = 0; r < 4; ++r) {
            const size_t rowg = (size_t)b * kS + (size_t)(q0 + wrow0 + 4 * g + r);
            const int d = 16 * dt + c;
            ctx[rowg * kD + d] = accpv[dt][r] + qg[rowg * kD + d];
        }
    }
}

}  // namespace

extern "C" void kernel_launch(void* const* d_in, const int* in_sizes, int n_in,
                              void* d_out, int out_size, void* d_ws, size_t ws_size,
                              hipStream_t stream) {
    const float* q = (const float*)d_in[0];
    const float* k = (const float*)d_in[1];
    const float* v = (const float*)d_in[2];
    float* out = (float*)d_out;
    dim3 grid(kB * (kS / BQ));
    dim3 block(512);
    hipLaunchKernelGGL(sdpa_kernel, grid, block, 0, stream, q, k, v, out);
}